// Round 2
// baseline (585.367 us; speedup 1.0000x reference)
//
#include <hip/hip_runtime.h>
#include <hip/hip_cooperative_groups.h>
#include <math.h>

namespace cg = cooperative_groups;

#define LM 64      // L_MODES
#define MM 127     // 2L-1
#define GG 128     // GRID
#define CC 64      // CIN
#define OO 64      // COUT
#define NBLK 512

#define TWO_PI 6.28318530717958647692f

// One persistent cooperative kernel, 512 blocks x 256 threads (2 blocks/CU).
// Phases (grid.sync between):
//  P1: DFT tiles (t, cq) 128x4=512 + block0 computes aux (time-MLP)
//  P2: forward Legendre partials (m, lh, tq) 64x2x4=512
//  P3: complex channel mix, 8128 (l,mi) tiles strided over 512 blocks
//  P4: inverse Legendre, 1016 (mi,y) tiles strided over 512 blocks
//  P5: Fourier synthesis + time branch + LN + ReLU, (t, kq) 128x4=512
__global__ __launch_bounds__(256, 2) void k_fused(
    const float* __restrict__ x, const float* __restrict__ t_emb,
    const float* __restrict__ wr, const float* __restrict__ wi,
    const float* __restrict__ conv_w, const float* __restrict__ conv_b,
    const float* __restrict__ time_w, const float* __restrict__ dense_w,
    const float* __restrict__ ln_scale, const float* __restrict__ ln_bias,
    const float* __restrict__ P_in, const float* __restrict__ P_out,
    const float* __restrict__ quad_w,
    float2* __restrict__ F, float2* __restrict__ flmp,
    float2* __restrict__ flm2, float2* __restrict__ g,
    float* __restrict__ Sv, float* __restrict__ aux,
    float* __restrict__ out)
{
    cg::grid_group grid = cg::this_grid();
    int b = blockIdx.x;
    int tx = threadIdx.x;

    __shared__ __align__(16) union {
        struct { float xs[GG * 16]; float2 tab[GG]; float cwsl[16];
                 float Sp[2][GG]; float bsum; } p1;             // ~10.3 KB
        float psis[128];                                        // aliases p1 (block0 aux)
        struct { float2 Fs[32 * 64]; float Ps[32 * 36]; } p2;   // 21 KB
        struct { float2 fs[CC]; float2 part[16][CC]; } p3;      // 8.75 KB
        struct { float2 Ws[64 * 32]; float Ps[64 * 32]; } p4;   // 24 KB
        struct { float2 gs[64 * 64]; float Ss[32]; } p5;        // 32.1 KB
    } u;

    // ------------------------------------------------------------- P1: DFT
    {
        int t = b >> 2, cq = b & 3;
        int c0base = cq * 16;

        const float* xp = x + (size_t)t * GG * CC + c0base;
        for (int idx = tx; idx < GG * 16 / 4; idx += 256) {
            int n = idx >> 2, c4 = idx & 3;
            *(float4*)&u.p1.xs[n * 16 + c4 * 4] = *(const float4*)&xp[n * CC + c4 * 4];
        }
        if (tx < GG) {
            float ang = (TWO_PI / GG) * tx;
            u.p1.tab[tx] = make_float2(cosf(ang), sinf(ang));
        }
        if (tx >= 128 && tx < 144) {
            int c = c0base + (tx - 128);
            float s = 0.f;
            for (int o = 0; o < OO; ++o) s += conv_w[c * OO + o];
            u.p1.cwsl[tx - 128] = s;
        }
        if (tx == 144) {
            float bs = 0.f;
            for (int o = 0; o < OO; ++o) bs += conv_b[o];
            u.p1.bsum = bs;
        }
        __syncthreads();

        int k = tx & 63, cgrp = tx >> 6;
        int c0 = cgrp * 4;

        float sr[4], si[4];
#pragma unroll
        for (int j = 0; j < 4; ++j) { sr[j] = 0.f; si[j] = 0.f; }

        int kn = 0;
#pragma unroll 4
        for (int n = 0; n < GG; ++n) {
            float2 w = u.p1.tab[kn];
            const float4 v = *(const float4*)&u.p1.xs[n * 16 + c0];
            float vv[4] = {v.x, v.y, v.z, v.w};
#pragma unroll
            for (int j = 0; j < 4; ++j) {
                sr[j] += vv[j] * w.x;
                si[j] -= vv[j] * w.y;
            }
            kn = (kn + k) & (GG - 1);
        }
        float sc = (TWO_PI / GG) * quad_w[t];
        {
            float2* Fp = F + ((size_t)t * 64 + k) * CC + c0base + c0;
            *(float4*)&Fp[0] = make_float4(sr[0] * sc, si[0] * sc, sr[1] * sc, si[1] * sc);
            *(float4*)&Fp[2] = make_float4(sr[2] * sc, si[2] * sc, sr[3] * sc, si[3] * sc);
        }

        // conv channel-sum partial over this block's 16 channels
        {
            int n2 = tx & 127, h = tx >> 7;
            float p = 0.f;
#pragma unroll
            for (int j = 0; j < 8; ++j) p += u.p1.xs[n2 * 16 + h * 8 + j] * u.p1.cwsl[h * 8 + j];
            u.p1.Sp[h][n2] = p;
        }
        __syncthreads();
        if (tx < GG) {
            float v = u.p1.Sp[0][tx] + u.p1.Sp[1][tx] + (cq == 0 ? u.p1.bsum : 0.f);
            Sv[(size_t)cq * GG * GG + t * GG + tx] = v;
        }

        if (b == 0) {  // time-MLP (tiny)
            __syncthreads();
            if (tx < 128) {
                float acc = 0.f;
                for (int tq = 0; tq < 256; ++tq) acc += t_emb[tq] * dense_w[tq * 128 + tx];
                u.psis[tx] = acc;
                aux[tx] = acc;
            }
            __syncthreads();
            if (tx < 64) {
                float tv = 0.f;
                for (int q = 0; q < 64; ++q) tv += time_w[tx * 64 + q] * u.psis[q];
                aux[128 + tx] = tv;
            }
        }
    }
    grid.sync();

    // ---------------------------------------------------- P2: fwd Legendre
    {
        int m = b & 63, lh = (b >> 6) & 1, tq = b >> 7;
        int l0 = lh * 32, t0 = tq * 32;
        if (l0 + 31 >= m) {
            int c = tx & 63, lg = tx >> 6;

            for (int idx = tx; idx < 32 * 32; idx += 256) {
                int lr = idx >> 5, tl = idx & 31;
                u.p2.Ps[tl * 36 + lr] = P_in[((size_t)(l0 + lr) * MM + 63 + m) * GG + t0 + tl];
            }
            for (int idx = tx; idx < 32 * 64; idx += 256) {
                int tl = idx >> 6, cc = idx & 63;
                u.p2.Fs[idx] = F[((size_t)(t0 + tl) * 64 + m) * CC + cc];
            }
            __syncthreads();

            float sr[8], si[8];
#pragma unroll
            for (int j = 0; j < 8; ++j) { sr[j] = 0.f; si[j] = 0.f; }

#pragma unroll 2
            for (int tl = 0; tl < 32; ++tl) {
                float2 f = u.p2.Fs[tl * 64 + c];
                const float* pp = &u.p2.Ps[tl * 36 + lg * 8];
                float4 p0 = *(const float4*)pp;
                float4 p1 = *(const float4*)(pp + 4);
                float pv[8] = {p0.x, p0.y, p0.z, p0.w, p1.x, p1.y, p1.z, p1.w};
#pragma unroll
                for (int j = 0; j < 8; ++j) {
                    sr[j] += f.x * pv[j];
                    si[j] += f.y * pv[j];
                }
            }
#pragma unroll
            for (int j = 0; j < 8; ++j) {
                int l = l0 + lg * 8 + j;
                if (l >= m)
                    flmp[(((size_t)tq * 64 + l) * 64 + m) * CC + c] = make_float2(sr[j], si[j]);
            }
        }
    }
    grid.sync();

    // ------------------------------------------------------- P3: weight mix
    for (int tt = b; tt < 64 * MM; tt += NBLK) {
        int l = tt / MM, mi = tt % MM;
        int m = mi - 63;
        int am = m < 0 ? -m : m;
        if (l < am) {
            if (tx < 64) flm2[(size_t)(l * MM + mi) * OO + tx] = make_float2(0.f, 0.f);
            continue;
        }
        int ol = tx & 15, ig = tx >> 4;
        if (tx < 64) {
            float2 f = make_float2(0.f, 0.f);
#pragma unroll
            for (int q = 0; q < 4; ++q) {
                float2 v = flmp[(((size_t)q * 64 + l) * 64 + am) * CC + tx];
                f.x += v.x;
                f.y += v.y;
            }
            if (m < 0) {
                float sgn = (am & 1) ? -1.f : 1.f;
                f.x *= sgn;
                f.y *= -sgn;
            }
            u.p3.fs[tx] = f;
        }
        __syncthreads();
        size_t base = ((size_t)(l * MM + mi) * CC) * OO;
        const float4* wr4 = (const float4*)(wr + base);
        const float4* wi4 = (const float4*)(wi + base);
        float ar[4] = {0.f, 0.f, 0.f, 0.f}, ai[4] = {0.f, 0.f, 0.f, 0.f};
#pragma unroll
        for (int di = 0; di < 4; ++di) {
            int i = ig * 4 + di;
            float4 a = wr4[i * 16 + ol];
            float4 bb = wi4[i * 16 + ol];
            float2 f = u.p3.fs[i];
            ar[0] += f.x * a.x - f.y * bb.x;  ai[0] += f.x * bb.x + f.y * a.x;
            ar[1] += f.x * a.y - f.y * bb.y;  ai[1] += f.x * bb.y + f.y * a.y;
            ar[2] += f.x * a.z - f.y * bb.z;  ai[2] += f.x * bb.z + f.y * a.z;
            ar[3] += f.x * a.w - f.y * bb.w;  ai[3] += f.x * bb.w + f.y * a.w;
        }
#pragma unroll
        for (int j = 0; j < 4; ++j) u.p3.part[ig][ol * 4 + j] = make_float2(ar[j], ai[j]);
        __syncthreads();
        if (tx < 64) {
            float rr = 0.f, ri = 0.f;
#pragma unroll
            for (int q = 0; q < 16; ++q) {
                float2 p = u.p3.part[q][tx];
                rr += p.x;
                ri += p.y;
            }
            flm2[(size_t)(l * MM + mi) * OO + tx] = make_float2(rr, ri);
        }
        __syncthreads();  // part-readers done before next tile's part writes
    }
    grid.sync();

    // ---------------------------------------------------- P4: inv Legendre
    for (int tt = b; tt < MM * 8; tt += NBLK) {
        int mi = tt % MM, y = tt / MM;
        int th = y >> 1, oh = y & 1;
        int t0 = th * 32, o0 = oh * 32;
        int ol = tx & 31, tg = tx >> 5;
        int o = o0 + ol;

        __syncthreads();  // previous tile's LDS readers done
        for (int idx = tx; idx < 64 * 32; idx += 256) {
            int ls = idx >> 5, oo = idx & 31;
            u.p4.Ws[idx] = flm2[(size_t)(ls * MM + mi) * OO + o0 + oo];
        }
        for (int idx = tx; idx < 64 * 32; idx += 256) {
            int ls = idx >> 5, t2 = idx & 31;
            u.p4.Ps[idx] = P_out[((size_t)ls * MM + mi) * GG + t0 + t2];
        }
        __syncthreads();

        float gr[4], gi[4];
#pragma unroll
        for (int j = 0; j < 4; ++j) { gr[j] = 0.f; gi[j] = 0.f; }

#pragma unroll 2
        for (int l = 0; l < 64; ++l) {
            float2 wv = u.p4.Ws[l * 32 + ol];
            const float4 p = *(const float4*)&u.p4.Ps[l * 32 + tg * 4];
            float pv[4] = {p.x, p.y, p.z, p.w};
#pragma unroll
            for (int j = 0; j < 4; ++j) {
                gr[j] += wv.x * pv[j];
                gi[j] += wv.y * pv[j];
            }
        }
#pragma unroll
        for (int j = 0; j < 4; ++j) {
            int t = t0 + tg * 4 + j;
            g[((size_t)t * MM + mi) * OO + o] = make_float2(gr[j], gi[j]);
        }
    }
    grid.sync();

    // ------------------------- P5: Fourier synthesis + time branch + LN/ReLU
    {
        int t = b >> 2, kq = b & 3;
        int o = tx & 63, kg = tx >> 6;   // kg 0..3, one wave per kg

        if (tx < 32) {
            float s = 0.f;
#pragma unroll
            for (int q = 0; q < 4; ++q)
                s += Sv[(size_t)q * GG * GG + t * GG + kq * 32 + tx];
            u.p5.Ss[tx] = s;
        }

        float zr[8], zi[8], accr[8], acci[8];
#pragma unroll
        for (int j = 0; j < 8; ++j) {
            int k = kq * 32 + kg * 8 + j;
            float phi = (TWO_PI / GG) * k;
            float s, c;
            sincosf(phi, &s, &c);
            zr[j] = c; zi[j] = s;
            accr[j] = 0.f; acci[j] = 0.f;
        }

        for (int pass = 0; pass < 2; ++pass) {
            int mbase = (pass == 0) ? 64 : 0;
            int cnt = (pass == 0) ? 63 : 64;
            __syncthreads();
            for (int idx = tx; idx < cnt * 64; idx += 256) {
                int mm = idx >> 6, oo = idx & 63;
                u.p5.gs[idx] = g[((size_t)t * MM + mbase + mm) * OO + oo];
            }
            __syncthreads();
            for (int mm = cnt - 1; mm >= 0; --mm) {
                float2 gv = u.p5.gs[mm * 64 + o];
#pragma unroll
                for (int j = 0; j < 8; ++j) {
                    float tr = accr[j] * zr[j] - acci[j] * zi[j] + gv.x;
                    float ti = accr[j] * zi[j] + acci[j] * zr[j] + gv.y;
                    accr[j] = tr; acci[j] = ti;
                }
            }
        }

        float tvec = aux[128 + o], bt = aux[64 + o];
        float lns = ln_scale[o], lnb = ln_bias[o];
#pragma unroll
        for (int j = 0; j < 8; ++j) {
            int k = kq * 32 + kg * 8 + j;
            float sgn = (k & 1) ? -1.f : 1.f;
            float xsp = sgn * (accr[j] * zr[j] - acci[j] * zi[j]);
            float val = xsp + tvec * u.p5.Ss[kg * 8 + j] + bt;

            float mu = val;
#pragma unroll
            for (int off = 1; off < 64; off <<= 1) mu += __shfl_xor(mu, off);
            mu *= (1.f / 64.f);
            float d = val - mu;
            float var = d * d;
#pragma unroll
            for (int off = 1; off < 64; off <<= 1) var += __shfl_xor(var, off);
            var *= (1.f / 64.f);
            float r = d * rsqrtf(var + 1e-6f) * lns + lnb;
            out[((size_t)(t * GG) + k) * OO + o] = fmaxf(r, 0.f);
        }
    }
}

// ---------------------------------------------------------------------------
extern "C" void kernel_launch(void* const* d_in, const int* in_sizes, int n_in,
                              void* d_out, int out_size, void* d_ws, size_t ws_size,
                              hipStream_t stream) {
    const float* x        = (const float*)d_in[0];
    const float* t_emb    = (const float*)d_in[1];
    const float* wr       = (const float*)d_in[2];
    const float* wi       = (const float*)d_in[3];
    const float* conv_w   = (const float*)d_in[4];
    const float* conv_b   = (const float*)d_in[5];
    const float* time_w   = (const float*)d_in[6];
    const float* dense_w  = (const float*)d_in[7];
    const float* ln_scale = (const float*)d_in[8];
    const float* ln_bias  = (const float*)d_in[9];
    const float* P_in     = (const float*)d_in[10];
    const float* P_out    = (const float*)d_in[11];
    const float* quad_w   = (const float*)d_in[12];

    float* ws = (float*)d_ws;
    float*  aux  = ws;                         // 512 floats
    float2* F    = (float2*)(ws + 512);        // 524288 f2  -> ends 1049088
    float2* flmp = (float2*)(ws + 1049088);    // 4x262144 f2 -> ends 3146240
    float2* flm2 = (float2*)(ws + 3146240);    // 520192 f2  -> ends 4186624
    float2* g    = (float2*)(ws + 4186624);    // 1040384 f2 -> ends 6267392
    float*  Sv   = ws + 6267392;               // 65536 (4 x 128 x 128)

    float* outp = (float*)d_out;

    void* args[] = {(void*)&x, (void*)&t_emb, (void*)&wr, (void*)&wi,
                    (void*)&conv_w, (void*)&conv_b, (void*)&time_w, (void*)&dense_w,
                    (void*)&ln_scale, (void*)&ln_bias, (void*)&P_in, (void*)&P_out,
                    (void*)&quad_w, (void*)&F, (void*)&flmp, (void*)&flm2,
                    (void*)&g, (void*)&Sv, (void*)&aux, (void*)&outp};
    hipLaunchCooperativeKernel((void*)k_fused, dim3(NBLK), dim3(256), args, 0, stream);
}

// Round 3
// 334.575 us; speedup vs baseline: 1.7496x; 1.7496x over previous
//
#include <hip/hip_runtime.h>
#include <math.h>

#define LM 64      // L_MODES
#define MM 127     // 2L-1
#define GG 128     // GRID
#define CC 64      // CIN
#define OO 64      // COUT

#define TWO_PI 6.28318530717958647692f

// ---------------------------------------------------------------------------
// K1: fused DFT + conv-channel-sum + (block 512) time-MLP precompute.
__global__ __launch_bounds__(256) void k_dft(const float* __restrict__ x,
                                             const float* __restrict__ quad_w,
                                             const float* __restrict__ conv_w,
                                             const float* __restrict__ conv_b,
                                             const float* __restrict__ t_emb,
                                             const float* __restrict__ dense_w,
                                             const float* __restrict__ time_w,
                                             float2* __restrict__ F,
                                             float* __restrict__ Sv,
                                             float* __restrict__ aux) {
    int b = blockIdx.x;
    int tx = threadIdx.x;

    if (b == 512) {
        // time-MLP: psi = t_emb @ dense_w ; tvec[o] = sum_j time_w[o,j]*psi[j]
        __shared__ float psis[128];
        if (tx < 128) {
            float acc = 0.f;
            for (int tq = 0; tq < 256; ++tq) acc += t_emb[tq] * dense_w[tq * 128 + tx];
            psis[tx] = acc;
            aux[tx] = acc;
        }
        __syncthreads();
        if (tx < 64) {
            float tv = 0.f;
            for (int q = 0; q < 64; ++q) tv += time_w[tx * 64 + q] * psis[q];
            aux[128 + tx] = tv;
        }
        return;
    }

    int t = b >> 2, cq = b & 3;
    int c0base = cq * 16;

    __shared__ __align__(16) float xs[GG * 16];  // [n][c-local] 8 KB
    __shared__ float2 tab[GG];
    __shared__ float cwsl[16];
    __shared__ float Sp[2][GG];
    __shared__ float bsum_s;

    // stage x[t][:, c0base..c0base+16) -- float4 coalesced
    {
        const float* xp = x + (size_t)t * GG * CC + c0base;
        for (int idx = tx; idx < GG * 16 / 4; idx += 256) {
            int n = idx >> 2, c4 = idx & 3;
            *(float4*)&xs[n * 16 + c4 * 4] = *(const float4*)&xp[n * CC + c4 * 4];
        }
    }
    if (tx < GG) {
        float ang = (TWO_PI / GG) * tx;
        tab[tx] = make_float2(cosf(ang), sinf(ang));
    }
    if (tx >= 128 && tx < 144) {
        int c = c0base + (tx - 128);
        float s = 0.f;
        for (int o = 0; o < OO; ++o) s += conv_w[c * OO + o];
        cwsl[tx - 128] = s;
    }
    if (tx == 144) {
        float bs = 0.f;
        for (int o = 0; o < OO; ++o) bs += conv_b[o];
        bsum_s = bs;
    }
    __syncthreads();

    int k = tx & 63, cg = tx >> 6;
    int c0 = cg * 4;

    float sr[4], si[4];
#pragma unroll
    for (int j = 0; j < 4; ++j) { sr[j] = 0.f; si[j] = 0.f; }

    int kn = 0;
#pragma unroll 4
    for (int n = 0; n < GG; ++n) {
        float2 w = tab[kn];
        const float4 v = *(const float4*)&xs[n * 16 + c0];
        float vv[4] = {v.x, v.y, v.z, v.w};
#pragma unroll
        for (int j = 0; j < 4; ++j) {
            sr[j] += vv[j] * w.x;
            si[j] -= vv[j] * w.y;
        }
        kn = (kn + k) & (GG - 1);
    }
    float sc = (TWO_PI / GG) * quad_w[t];

    {
        float2* Fp = F + ((size_t)t * 64 + k) * CC + c0base + c0;
        *(float4*)&Fp[0] = make_float4(sr[0] * sc, si[0] * sc, sr[1] * sc, si[1] * sc);
        *(float4*)&Fp[2] = make_float4(sr[2] * sc, si[2] * sc, sr[3] * sc, si[3] * sc);
    }

    // conv channel-sum partial over this block's 16 channels (xs still valid)
    {
        int n2 = tx & 127, h = tx >> 7;  // h in {0,1}, 8 channels each
        float p = 0.f;
#pragma unroll
        for (int j = 0; j < 8; ++j) p += xs[n2 * 16 + h * 8 + j] * cwsl[h * 8 + j];
        Sp[h][n2] = p;
    }
    __syncthreads();
    if (tx < GG) {
        float v = Sp[0][tx] + Sp[1][tx] + (cq == 0 ? bsum_s : 0.f);
        Sv[(size_t)cq * GG * GG + t * GG + tx] = v;
    }
}

// ---------------------------------------------------------------------------
// K2: forward Legendre, t-split 4 ways into partial sums.
__global__ __launch_bounds__(256) void k_leg_fwd(const float2* __restrict__ F,
                                                 const float* __restrict__ P_in,
                                                 float2* __restrict__ flmp) {
    int m = blockIdx.x;      // 0..63
    int lh = blockIdx.y;     // 0..1
    int tq = blockIdx.z;     // 0..3
    int l0 = lh * 32;
    if (l0 + 31 < m) return;
    int t0 = tq * 32;

    __shared__ __align__(16) float2 Fs[32 * 64];   // 16 KB
    __shared__ __align__(16) float  Ps[32 * 36];   // 4.5 KB
    int tx = threadIdx.x;
    int c = tx & 63, lg = tx >> 6;

    for (int idx = tx; idx < 32 * 32; idx += 256) {
        int lr = idx >> 5, tl = idx & 31;
        Ps[tl * 36 + lr] = P_in[((size_t)(l0 + lr) * MM + 63 + m) * GG + t0 + tl];
    }
    for (int idx = tx; idx < 32 * 64; idx += 256) {
        int tl = idx >> 6, cc = idx & 63;
        Fs[idx] = F[((size_t)(t0 + tl) * 64 + m) * CC + cc];
    }
    __syncthreads();

    float sr[8], si[8];
#pragma unroll
    for (int j = 0; j < 8; ++j) { sr[j] = 0.f; si[j] = 0.f; }

#pragma unroll 2
    for (int tl = 0; tl < 32; ++tl) {
        float2 f = Fs[tl * 64 + c];
        const float* pp = &Ps[tl * 36 + lg * 8];
        float4 p0 = *(const float4*)pp;
        float4 p1 = *(const float4*)(pp + 4);
        float pv[8] = {p0.x, p0.y, p0.z, p0.w, p1.x, p1.y, p1.z, p1.w};
#pragma unroll
        for (int j = 0; j < 8; ++j) {
            sr[j] += f.x * pv[j];
            si[j] += f.y * pv[j];
        }
    }
#pragma unroll
    for (int j = 0; j < 8; ++j) {
        int l = l0 + lg * 8 + j;
        if (l >= m)
            flmp[(((size_t)tq * 64 + l) * 64 + m) * CC + c] = make_float2(sr[j], si[j]);
    }
}

// ---------------------------------------------------------------------------
// K3: complex channel mix — barrier-free streaming rewrite.
// One wave per (l,mi) tile: lane = o. f[i] lives in lane i, broadcast via
// v_readlane in a fully-unrolled i-loop. Weights streamed as coalesced b32.
// No LDS, no __syncthreads. 4 waves/block, 2032 blocks (~8 blocks/CU).
__global__ __launch_bounds__(256) void k_wmul(const float2* __restrict__ flmp,
                                              const float* __restrict__ wr,
                                              const float* __restrict__ wi,
                                              float2* __restrict__ flm2) {
    int wv = threadIdx.x >> 6;       // wave 0..3
    int lane = threadIdx.x & 63;
    int tt = blockIdx.x * 4 + wv;    // tile id
    if (tt >= 64 * MM) return;
    int l = tt / MM, mi = tt % MM;
    int m = mi - 63;
    int am = m < 0 ? -m : m;
    size_t obase = (size_t)(l * MM + mi) * OO;
    if (l < am) {
        flm2[obase + lane] = make_float2(0.f, 0.f);
        return;
    }

    // lane i accumulates f[i] = sum_q flmp[q][l][am][i] (with -m conjugation)
    float fx = 0.f, fy = 0.f;
#pragma unroll
    for (int q = 0; q < 4; ++q) {
        float2 v = flmp[(((size_t)q * 64 + l) * 64 + am) * CC + lane];
        fx += v.x;
        fy += v.y;
    }
    if (m < 0) {
        float sgn = (am & 1) ? -1.f : 1.f;
        fx *= sgn;
        fy *= -sgn;
    }

    size_t base = ((size_t)(l * MM + mi) * CC) * OO;
    const float* wrp = wr + base;
    const float* wip = wi + base;
    float ar = 0.f, ai = 0.f;
#pragma unroll
    for (int i = 0; i < CC; ++i) {
        float fxi = __uint_as_float(__builtin_amdgcn_readlane(__float_as_uint(fx), i));
        float fyi = __uint_as_float(__builtin_amdgcn_readlane(__float_as_uint(fy), i));
        float a = wrp[i * OO + lane];
        float bv = wip[i * OO + lane];
        ar += fxi * a - fyi * bv;
        ai += fxi * bv + fyi * a;
    }
    flm2[obase + lane] = make_float2(ar, ai);
}

// ---------------------------------------------------------------------------
// K4: inverse Legendre. Block per (mi, th(4) x oh(2)), 256 threads.
__global__ __launch_bounds__(256) void k_leg_inv(const float2* __restrict__ flm2,
                                                 const float* __restrict__ P_out,
                                                 float2* __restrict__ g) {
    int mi = blockIdx.x;
    int th = blockIdx.y >> 1, oh = blockIdx.y & 1;
    int t0 = th * 32, o0 = oh * 32;

    __shared__ __align__(16) float2 Ws[64 * 32]; // 16 KB
    __shared__ __align__(16) float  Ps[64 * 32]; // 8 KB
    int tx = threadIdx.x;
    int ol = tx & 31, tg = tx >> 5;   // tg in 0..7, 4 t each
    int o = o0 + ol;

    for (int idx = tx; idx < 64 * 32; idx += 256) {
        int ls = idx >> 5, oo = idx & 31;
        Ws[idx] = flm2[(size_t)(ls * MM + mi) * OO + o0 + oo];
    }
    for (int idx = tx; idx < 64 * 32; idx += 256) {
        int ls = idx >> 5, tt = idx & 31;
        Ps[idx] = P_out[((size_t)ls * MM + mi) * GG + t0 + tt];
    }
    __syncthreads();

    float gr[4], gi[4];
#pragma unroll
    for (int j = 0; j < 4; ++j) { gr[j] = 0.f; gi[j] = 0.f; }

#pragma unroll 2
    for (int l = 0; l < 64; ++l) {
        float2 wv = Ws[l * 32 + ol];
        const float4 p = *(const float4*)&Ps[l * 32 + tg * 4];
        float pv[4] = {p.x, p.y, p.z, p.w};
#pragma unroll
        for (int j = 0; j < 4; ++j) {
            gr[j] += wv.x * pv[j];
            gi[j] += wv.y * pv[j];
        }
    }
#pragma unroll
    for (int j = 0; j < 4; ++j) {
        int t = t0 + tg * 4 + j;
        g[((size_t)t * MM + mi) * OO + o] = make_float2(gr[j], gi[j]);
    }
}

// ---------------------------------------------------------------------------
// K5: Fourier synthesis (Horner) + time-mod branch + LN + ReLU.
// e^{-i63phi} via identity: 63phi = pi*k - phi  =>  c63 = (-1)^k c, s63 = -(-1)^k s.
__global__ __launch_bounds__(512) void k_final(const float2* __restrict__ g,
                                               const float* __restrict__ Sv,
                                               const float* __restrict__ aux,
                                               const float* __restrict__ ln_scale,
                                               const float* __restrict__ ln_bias,
                                               float* __restrict__ out) {
    __shared__ float2 gs[64 * 64]; // 32 KB, two mi-passes
    __shared__ float Ss[64];
    int t = blockIdx.x, kh = blockIdx.y;
    int tx = threadIdx.x;
    int o = tx & 63, kg = tx >> 6;

    if (tx < 64) {
        float s = 0.f;
#pragma unroll
        for (int q = 0; q < 4; ++q) s += Sv[(size_t)q * GG * GG + t * GG + kh * 64 + tx];
        Ss[tx] = s;
    }

    float zr[8], zi[8], accr[8], acci[8];
#pragma unroll
    for (int j = 0; j < 8; ++j) {
        int k = kh * 64 + kg * 8 + j;
        float phi = (TWO_PI / GG) * k;
        float s, c;
        sincosf(phi, &s, &c);   // precise, one-time
        zr[j] = c; zi[j] = s;
        accr[j] = 0.f; acci[j] = 0.f;
    }

    for (int pass = 0; pass < 2; ++pass) {
        int mbase = (pass == 0) ? 64 : 0;
        int cnt = (pass == 0) ? 63 : 64;
        __syncthreads();
        for (int idx = tx; idx < cnt * 64; idx += 512) {
            int mm = idx >> 6, oo = idx & 63;
            gs[idx] = g[((size_t)t * MM + mbase + mm) * OO + oo];
        }
        __syncthreads();
        for (int mm = cnt - 1; mm >= 0; --mm) {
            float2 gv = gs[mm * 64 + o];
#pragma unroll
            for (int j = 0; j < 8; ++j) {
                float tr = accr[j] * zr[j] - acci[j] * zi[j] + gv.x;
                float ti = accr[j] * zi[j] + acci[j] * zr[j] + gv.y;
                accr[j] = tr; acci[j] = ti;
            }
        }
    }

    float tvec = aux[128 + o], bt = aux[64 + o];
    float lns = ln_scale[o], lnb = ln_bias[o];
#pragma unroll
    for (int j = 0; j < 8; ++j) {
        int k = kh * 64 + kg * 8 + j;
        float sgn = (k & 1) ? -1.f : 1.f;
        float xsp = sgn * (accr[j] * zr[j] - acci[j] * zi[j]);
        float val = xsp + tvec * Ss[k - kh * 64] + bt;

        float mu = val;
#pragma unroll
        for (int off = 1; off < 64; off <<= 1) mu += __shfl_xor(mu, off);
        mu *= (1.f / 64.f);
        float d = val - mu;
        float var = d * d;
#pragma unroll
        for (int off = 1; off < 64; off <<= 1) var += __shfl_xor(var, off);
        var *= (1.f / 64.f);
        float r = d * rsqrtf(var + 1e-6f) * lns + lnb;
        out[((size_t)(t * GG) + k) * OO + o] = fmaxf(r, 0.f);
    }
}

// ---------------------------------------------------------------------------
extern "C" void kernel_launch(void* const* d_in, const int* in_sizes, int n_in,
                              void* d_out, int out_size, void* d_ws, size_t ws_size,
                              hipStream_t stream) {
    const float* x        = (const float*)d_in[0];
    const float* t_emb    = (const float*)d_in[1];
    const float* wr       = (const float*)d_in[2];
    const float* wi       = (const float*)d_in[3];
    const float* conv_w   = (const float*)d_in[4];
    const float* conv_b   = (const float*)d_in[5];
    const float* time_w   = (const float*)d_in[6];
    const float* dense_w  = (const float*)d_in[7];
    const float* ln_scale = (const float*)d_in[8];
    const float* ln_bias  = (const float*)d_in[9];
    const float* P_in     = (const float*)d_in[10];
    const float* P_out    = (const float*)d_in[11];
    const float* quad_w   = (const float*)d_in[12];

    float* ws = (float*)d_ws;
    float*  aux  = ws;                         // 512 floats
    float2* F    = (float2*)(ws + 512);        // 524288 f2  -> ends 1049088
    float2* flmp = (float2*)(ws + 1049088);    // 4x262144 f2 -> ends 3146240
    float2* flm2 = (float2*)(ws + 3146240);    // 520192 f2  -> ends 4186624
    float2* g    = (float2*)(ws + 4186624);    // 1040384 f2 -> ends 6267392
    float*  Sv   = ws + 6267392;               // 65536 (4 x 128 x 128)

    float* out = (float*)d_out;

    k_dft<<<513, 256, 0, stream>>>(x, quad_w, conv_w, conv_b, t_emb, dense_w, time_w,
                                   F, Sv, aux);
    k_leg_fwd<<<dim3(64, 2, 4), 256, 0, stream>>>(F, P_in, flmp);
    k_wmul<<<(64 * MM + 3) / 4, 256, 0, stream>>>(flmp, wr, wi, flm2);
    k_leg_inv<<<dim3(MM, 8), 256, 0, stream>>>(flm2, P_out, g);
    k_final<<<dim3(GG, 2), 512, 0, stream>>>(g, Sv, aux, ln_scale, ln_bias, out);
}

// Round 5
// 332.595 us; speedup vs baseline: 1.7600x; 1.0060x over previous
//
#include <hip/hip_runtime.h>
#include <math.h>

#define LM 64      // L_MODES
#define MM 127     // 2L-1
#define GG 128     // GRID
#define CC 64      // CIN
#define OO 64      // COUT

#define TWO_PI 6.28318530717958647692f

// ---------------------------------------------------------------------------
// K1: fused DFT + conv-channel-sum + (block 1024) time-MLP precompute.
// Blocks 0..1023: b = (t, ce). 8 channels per block. 256 threads:
//   k = tx&63, cgrp = tx>>6 (2 ch each).
__global__ __launch_bounds__(256) void k_dft(const float* __restrict__ x,
                                             const float* __restrict__ quad_w,
                                             const float* __restrict__ conv_w,
                                             const float* __restrict__ conv_b,
                                             const float* __restrict__ t_emb,
                                             const float* __restrict__ dense_w,
                                             const float* __restrict__ time_w,
                                             float2* __restrict__ F,
                                             float* __restrict__ Sv,
                                             float* __restrict__ aux) {
    int b = blockIdx.x;
    int tx = threadIdx.x;

    if (b == 1024) {
        // time-MLP: psi = t_emb @ dense_w ; tvec[o] = sum_j time_w[o,j]*psi[j]
        __shared__ float psis[128];
        if (tx < 128) {
            float acc = 0.f;
            for (int tq = 0; tq < 256; ++tq) acc += t_emb[tq] * dense_w[tq * 128 + tx];
            psis[tx] = acc;
            aux[tx] = acc;
        }
        __syncthreads();
        if (tx < 64) {
            float tv = 0.f;
            for (int q = 0; q < 64; ++q) tv += time_w[tx * 64 + q] * psis[q];
            aux[128 + tx] = tv;
        }
        return;
    }

    int t = b >> 3, ce = b & 7;
    int c0base = ce * 8;

    __shared__ __align__(16) float xs[GG * 8];  // [n][c-local] 4 KB
    __shared__ float cs[GG], sn[GG];
    __shared__ float cwsl[8];
    __shared__ float Sp[2][GG];
    __shared__ float bsum_s;

    // stage x[t][:, c0base..c0base+8) -- one float4 per thread
    {
        const float* xp = x + (size_t)t * GG * CC + c0base;
        int n = tx >> 1, c4 = tx & 1;
        *(float4*)&xs[n * 8 + c4 * 4] = *(const float4*)&xp[n * CC + c4 * 4];
    }
    if (tx < GG) {
        float ang = (TWO_PI / GG) * tx;
        cs[tx] = cosf(ang);
        sn[tx] = sinf(ang);
    }
    if (tx >= 128 && tx < 136) {
        int c = c0base + (tx - 128);
        float s = 0.f;
        for (int o = 0; o < OO; ++o) s += conv_w[c * OO + o];
        cwsl[tx - 128] = s;
    }
    if (tx == 136) {
        float bs = 0.f;
        for (int o = 0; o < OO; ++o) bs += conv_b[o];
        bsum_s = bs;
    }
    __syncthreads();

    int k = tx & 63, cgrp = tx >> 6;
    int c0 = cgrp * 2;

    float sr0 = 0.f, si0 = 0.f, sr1 = 0.f, si1 = 0.f;
    int kn = 0;
#pragma unroll 8
    for (int n = 0; n < GG; ++n) {
        float wx = cs[kn], wy = sn[kn];
        float2 v = *(const float2*)&xs[n * 8 + c0];
        sr0 += v.x * wx;
        si0 -= v.x * wy;
        sr1 += v.y * wx;
        si1 -= v.y * wy;
        kn = (kn + k) & (GG - 1);
    }
    float sc = (TWO_PI / GG) * quad_w[t];

    {
        float2* Fp = F + ((size_t)t * 64 + k) * CC + c0base + c0;
        *(float4*)&Fp[0] = make_float4(sr0 * sc, si0 * sc, sr1 * sc, si1 * sc);
    }

    // conv channel-sum partial over this block's 8 channels (xs still valid)
    {
        int n2 = tx & 127, h = tx >> 7;  // h in {0,1}, 4 channels each
        float p = 0.f;
#pragma unroll
        for (int j = 0; j < 4; ++j) p += xs[n2 * 8 + h * 4 + j] * cwsl[h * 4 + j];
        Sp[h][n2] = p;
    }
    __syncthreads();
    if (tx < GG) {
        float v = Sp[0][tx] + Sp[1][tx] + (ce == 0 ? bsum_s : 0.f);
        Sv[(size_t)ce * GG * GG + t * GG + tx] = v;
    }
}

// ---------------------------------------------------------------------------
// K2: forward Legendre, t-split 4 x l-split 4.
// Block per (m, lq, tq). 256 threads: c = tx&63, lg = tx>>6 (4 l each).
__global__ __launch_bounds__(256) void k_leg_fwd(const float2* __restrict__ F,
                                                 const float* __restrict__ P_in,
                                                 float2* __restrict__ flmp) {
    int m = blockIdx.x;      // 0..63
    int lq = blockIdx.y;     // 0..3
    int tq = blockIdx.z;     // 0..3
    int l0 = lq * 16;
    if (l0 + 15 < m) return;
    int t0 = tq * 32;

    __shared__ __align__(16) float2 Fs[32 * 64];   // 16 KB
    __shared__ __align__(16) float  Ps[32 * 20];   // 2.5 KB
    int tx = threadIdx.x;
    int c = tx & 63, lg = tx >> 6;

    for (int idx = tx; idx < 16 * 32; idx += 256) {
        int lr = idx >> 5, tl = idx & 31;
        Ps[tl * 20 + lr] = P_in[((size_t)(l0 + lr) * MM + 63 + m) * GG + t0 + tl];
    }
    for (int idx = tx; idx < 32 * 64; idx += 256) {
        int tl = idx >> 6, cc = idx & 63;
        Fs[idx] = F[((size_t)(t0 + tl) * 64 + m) * CC + cc];
    }
    __syncthreads();

    float sr[4], si[4];
#pragma unroll
    for (int j = 0; j < 4; ++j) { sr[j] = 0.f; si[j] = 0.f; }

#pragma unroll 4
    for (int tl = 0; tl < 32; ++tl) {
        float2 f = Fs[tl * 64 + c];
        float4 p0 = *(const float4*)&Ps[tl * 20 + lg * 4];
        float pv[4] = {p0.x, p0.y, p0.z, p0.w};
#pragma unroll
        for (int j = 0; j < 4; ++j) {
            sr[j] += f.x * pv[j];
            si[j] += f.y * pv[j];
        }
    }
#pragma unroll
    for (int j = 0; j < 4; ++j) {
        int l = l0 + lg * 4 + j;
        if (l >= m)
            flmp[(((size_t)tq * 64 + l) * 64 + m) * CC + c] = make_float2(sr[j], si[j]);
    }
}

// ---------------------------------------------------------------------------
// K3: complex channel mix — barrier-free streaming (unchanged from r3).
__global__ __launch_bounds__(256) void k_wmul(const float2* __restrict__ flmp,
                                              const float* __restrict__ wr,
                                              const float* __restrict__ wi,
                                              float2* __restrict__ flm2) {
    int wv = threadIdx.x >> 6;       // wave 0..3
    int lane = threadIdx.x & 63;
    int tt = blockIdx.x * 4 + wv;    // tile id
    if (tt >= 64 * MM) return;
    int l = tt / MM, mi = tt % MM;
    int m = mi - 63;
    int am = m < 0 ? -m : m;
    size_t obase = (size_t)(l * MM + mi) * OO;
    if (l < am) {
        flm2[obase + lane] = make_float2(0.f, 0.f);
        return;
    }

    float fx = 0.f, fy = 0.f;
#pragma unroll
    for (int q = 0; q < 4; ++q) {
        float2 v = flmp[(((size_t)q * 64 + l) * 64 + am) * CC + lane];
        fx += v.x;
        fy += v.y;
    }
    if (m < 0) {
        float sgn = (am & 1) ? -1.f : 1.f;
        fx *= sgn;
        fy *= -sgn;
    }

    size_t base = ((size_t)(l * MM + mi) * CC) * OO;
    const float* wrp = wr + base;
    const float* wip = wi + base;
    float ar = 0.f, ai = 0.f;
#pragma unroll
    for (int i = 0; i < CC; ++i) {
        float fxi = __uint_as_float(__builtin_amdgcn_readlane(__float_as_uint(fx), i));
        float fyi = __uint_as_float(__builtin_amdgcn_readlane(__float_as_uint(fy), i));
        float a = wrp[i * OO + lane];
        float bv = wip[i * OO + lane];
        ar += fxi * a - fyi * bv;
        ai += fxi * bv + fyi * a;
    }
    flm2[obase + lane] = make_float2(ar, ai);
}

// ---------------------------------------------------------------------------
// K4: inverse Legendre. Block per (mi, th(4) x oh(2)), 256 threads.
__global__ __launch_bounds__(256) void k_leg_inv(const float2* __restrict__ flm2,
                                                 const float* __restrict__ P_out,
                                                 float2* __restrict__ g) {
    int mi = blockIdx.x;
    int th = blockIdx.y >> 1, oh = blockIdx.y & 1;
    int t0 = th * 32, o0 = oh * 32;

    __shared__ __align__(16) float2 Ws[64 * 32]; // 16 KB
    __shared__ __align__(16) float  Ps[64 * 32]; // 8 KB
    int tx = threadIdx.x;
    int ol = tx & 31, tg = tx >> 5;   // tg in 0..7, 4 t each
    int o = o0 + ol;

    for (int idx = tx; idx < 64 * 32; idx += 256) {
        int ls = idx >> 5, oo = idx & 31;
        Ws[idx] = flm2[(size_t)(ls * MM + mi) * OO + o0 + oo];
    }
    for (int idx = tx; idx < 64 * 32; idx += 256) {
        int ls = idx >> 5, tt = idx & 31;
        Ps[idx] = P_out[((size_t)ls * MM + mi) * GG + t0 + tt];
    }
    __syncthreads();

    float gr[4], gi[4];
#pragma unroll
    for (int j = 0; j < 4; ++j) { gr[j] = 0.f; gi[j] = 0.f; }

#pragma unroll 2
    for (int l = 0; l < 64; ++l) {
        float2 wv = Ws[l * 32 + ol];
        const float4 p = *(const float4*)&Ps[l * 32 + tg * 4];
        float pv[4] = {p.x, p.y, p.z, p.w};
#pragma unroll
        for (int j = 0; j < 4; ++j) {
            gr[j] += wv.x * pv[j];
            gi[j] += wv.y * pv[j];
        }
    }
#pragma unroll
    for (int j = 0; j < 4; ++j) {
        int t = t0 + tg * 4 + j;
        g[((size_t)t * MM + mi) * OO + o] = make_float2(gr[j], gi[j]);
    }
}

// ---------------------------------------------------------------------------
// K5: Fourier synthesis (Horner) + time-mod branch + LN + ReLU.
// Grid (t, kq 0..3), 512 threads: o = tx&63, kg = tx>>6 (4 k each).
// e^{-i63phi} via identity: 63phi = pi*k - phi.
__global__ __launch_bounds__(512) void k_final(const float2* __restrict__ g,
                                               const float* __restrict__ Sv,
                                               const float* __restrict__ aux,
                                               const float* __restrict__ ln_scale,
                                               const float* __restrict__ ln_bias,
                                               float* __restrict__ out) {
    __shared__ float2 gs[64 * 64]; // 32 KB, two mi-passes
    __shared__ float Ss[32];
    int t = blockIdx.x, kq = blockIdx.y;
    int tx = threadIdx.x;
    int o = tx & 63, kg = tx >> 6;   // kg 0..7

    if (tx < 32) {
        float s = 0.f;
#pragma unroll
        for (int q = 0; q < 8; ++q) s += Sv[(size_t)q * GG * GG + t * GG + kq * 32 + tx];
        Ss[tx] = s;
    }

    float zr[4], zi[4], accr[4], acci[4];
#pragma unroll
    for (int j = 0; j < 4; ++j) {
        int k = kq * 32 + kg * 4 + j;
        float phi = (TWO_PI / GG) * k;
        float s, c;
        sincosf(phi, &s, &c);
        zr[j] = c; zi[j] = s;
        accr[j] = 0.f; acci[j] = 0.f;
    }

    for (int pass = 0; pass < 2; ++pass) {
        int mbase = (pass == 0) ? 64 : 0;
        int cnt = (pass == 0) ? 63 : 64;
        __syncthreads();
        for (int idx = tx; idx < cnt * 64; idx += 512) {
            int mm = idx >> 6, oo = idx & 63;
            gs[idx] = g[((size_t)t * MM + mbase + mm) * OO + oo];
        }
        __syncthreads();
        for (int mm = cnt - 1; mm >= 0; --mm) {
            float2 gv = gs[mm * 64 + o];
#pragma unroll
            for (int j = 0; j < 4; ++j) {
                float tr = accr[j] * zr[j] - acci[j] * zi[j] + gv.x;
                float ti = accr[j] * zi[j] + acci[j] * zr[j] + gv.y;
                accr[j] = tr; acci[j] = ti;
            }
        }
    }

    float tvec = aux[128 + o], bt = aux[64 + o];
    float lns = ln_scale[o], lnb = ln_bias[o];
#pragma unroll
    for (int j = 0; j < 4; ++j) {
        int k = kq * 32 + kg * 4 + j;
        float sgn = (k & 1) ? -1.f : 1.f;
        float xsp = sgn * (accr[j] * zr[j] - acci[j] * zi[j]);
        float val = xsp + tvec * Ss[kg * 4 + j] + bt;

        float mu = val;
#pragma unroll
        for (int off = 1; off < 64; off <<= 1) mu += __shfl_xor(mu, off);
        mu *= (1.f / 64.f);
        float d = val - mu;
        float var = d * d;
#pragma unroll
        for (int off = 1; off < 64; off <<= 1) var += __shfl_xor(var, off);
        var *= (1.f / 64.f);
        float r = d * rsqrtf(var + 1e-6f) * lns + lnb;
        out[((size_t)(t * GG) + k) * OO + o] = fmaxf(r, 0.f);
    }
}

// ---------------------------------------------------------------------------
extern "C" void kernel_launch(void* const* d_in, const int* in_sizes, int n_in,
                              void* d_out, int out_size, void* d_ws, size_t ws_size,
                              hipStream_t stream) {
    const float* x        = (const float*)d_in[0];
    const float* t_emb    = (const float*)d_in[1];
    const float* wr       = (const float*)d_in[2];
    const float* wi       = (const float*)d_in[3];
    const float* conv_w   = (const float*)d_in[4];
    const float* conv_b   = (const float*)d_in[5];
    const float* time_w   = (const float*)d_in[6];
    const float* dense_w  = (const float*)d_in[7];
    const float* ln_scale = (const float*)d_in[8];
    const float* ln_bias  = (const float*)d_in[9];
    const float* P_in     = (const float*)d_in[10];
    const float* P_out    = (const float*)d_in[11];
    const float* quad_w   = (const float*)d_in[12];

    float* ws = (float*)d_ws;
    float*  aux  = ws;                         // 512 floats
    float2* F    = (float2*)(ws + 512);        // 524288 f2  -> ends 1049088
    float2* flmp = (float2*)(ws + 1049088);    // 4x262144 f2 -> ends 3146240
    float2* flm2 = (float2*)(ws + 3146240);    // 520192 f2  -> ends 4186624
    float2* g    = (float2*)(ws + 4186624);    // 1040384 f2 -> ends 6267392
    float*  Sv   = ws + 6267392;               // 131072 (8 x 128 x 128)

    float* out = (float*)d_out;

    k_dft<<<1025, 256, 0, stream>>>(x, quad_w, conv_w, conv_b, t_emb, dense_w, time_w,
                                    F, Sv, aux);
    k_leg_fwd<<<dim3(64, 4, 4), 256, 0, stream>>>(F, P_in, flmp);
    k_wmul<<<(64 * MM + 3) / 4, 256, 0, stream>>>(flmp, wr, wi, flm2);
    k_leg_inv<<<dim3(MM, 8), 256, 0, stream>>>(flm2, P_out, g);
    k_final<<<dim3(GG, 4), 512, 0, stream>>>(g, Sv, aux, ln_scale, ln_bias, out);
}